// Round 4
// baseline (1898.410 us; speedup 1.0000x reference)
//
#include <hip/hip_runtime.h>

#define NN 100000
#define NE 1600000
#define LAM 0.05f
#define NT32 (NE/32)

typedef __attribute__((ext_vector_type(8))) short bf16x8;
typedef __attribute__((ext_vector_type(8))) unsigned short u16x8;
typedef __attribute__((ext_vector_type(4))) float f32x4;

__device__ inline unsigned short f2bf(float x) {
  unsigned u = __builtin_bit_cast(unsigned, x);
  u = (u + 0x7FFFu + ((u >> 16) & 1u)) >> 16;
  return (unsigned short)u;
}
__device__ inline float bf2f(unsigned short h) {
  unsigned u = ((unsigned)h) << 16;
  return __builtin_bit_cast(float, u);
}
__device__ inline u16x8 pack2(float4 a, float4 b) {
  u16x8 p;
  p[0]=f2bf(a.x); p[1]=f2bf(a.y); p[2]=f2bf(a.z); p[3]=f2bf(a.w);
  p[4]=f2bf(b.x); p[5]=f2bf(b.y); p[6]=f2bf(b.z); p[7]=f2bf(b.w);
  return p;
}
__device__ inline u16x8 zero8() {
  u16x8 z;
  #pragma unroll
  for (int i = 0; i < 8; ++i) z[i] = 0;
  return z;
}
__device__ inline f32x4 zero4() {
  f32x4 z;
  z[0] = z[1] = z[2] = z[3] = 0.f;
  return z;
}

#define MFMA(a,b,c) __builtin_amdgcn_mfma_f32_16x16x32_bf16((bf16x8)(a),(bf16x8)(b),(c),0,0,0)

// ============ Kernel 1: V|T = H @ [Wv|Wt]^T via MFMA (unchanged) ============
#define K1S 136
__global__ __launch_bounds__(256) void k1_vt(
    const float* __restrict__ H, const float* __restrict__ Wv,
    const float* __restrict__ Wt, float* __restrict__ V, float* __restrict__ T)
{
  __shared__ unsigned short Wl[128*K1S];
  __shared__ unsigned short Hs[64*K1S];
  const int tid = threadIdx.x;
  for (int idx = tid; idx < 128*16; idx += 256) {
    int c = idx >> 4, k = (idx & 15) * 8;
    const float* src = (c < 64) ? (Wv + c*128 + k) : (Wt + (c-64)*128 + k);
    *(u16x8*)&Wl[c*K1S + k] = pack2(*(const float4*)src, *(const float4*)(src+4));
  }
  __syncthreads();
  const int wv = tid >> 6, l = tid & 63, l15 = l & 15, lh = l >> 4;
  const int ntiles = (NN + 63) >> 6;
  for (int t = blockIdx.x; t < ntiles; t += gridDim.x) {
    const int nb = t * 64;
    {
      const int r = tid >> 2, q = tid & 3, row = nb + r;
      if (row < NN) {
        const float* src = H + row*128 + q*32;
        #pragma unroll
        for (int s = 0; s < 4; ++s)
          *(u16x8*)&Hs[r*K1S + q*32 + s*8] =
              pack2(*(const float4*)(src + s*8), *(const float4*)(src + s*8 + 4));
      } else {
        #pragma unroll
        for (int s = 0; s < 4; ++s) *(u16x8*)&Hs[r*K1S + q*32 + s*8] = zero8();
      }
    }
    __syncthreads();
    f32x4 acc[4][2];
    #pragma unroll
    for (int m = 0; m < 4; ++m) { acc[m][0] = zero4(); acc[m][1] = zero4(); }
    #pragma unroll
    for (int kk = 0; kk < 128; kk += 32) {
      const int kb = kk + lh*8;
      bf16x8 bf0 = *(const bf16x8*)&Wl[(wv*32 + l15)*K1S + kb];
      bf16x8 bf1 = *(const bf16x8*)&Wl[(wv*32 + 16 + l15)*K1S + kb];
      #pragma unroll
      for (int m = 0; m < 4; ++m) {
        bf16x8 af = *(const bf16x8*)&Hs[(m*16 + l15)*K1S + kb];
        acc[m][0] = MFMA(af, bf0, acc[m][0]);
        acc[m][1] = MFMA(af, bf1, acc[m][1]);
      }
    }
    #pragma unroll
    for (int m = 0; m < 4; ++m) {
      const int rowl = m*16 + lh*4;
      #pragma unroll
      for (int n = 0; n < 2; ++n) {
        const int col = wv*32 + n*16 + l15;
        #pragma unroll
        for (int r = 0; r < 4; ++r) {
          const int node = nb + rowl + r;
          if (node < NN) {
            if (col < 64) V[node*64 + col] = acc[m][n][r];
            else          T[node*64 + col - 64] = acc[m][n][r];
          }
        }
      }
    }
    __syncthreads();
  }
}

// ============ Kernel 2: wave-autonomous edge MLP + scatter ============
// Each wave owns 32 edges (2 MFMA m-tiles). No per-tile barriers.
// A-fragments gathered straight from global (T/V rows are contiguous 256B),
// packed to bf16 in-register. Only w1 lives in LDS.
#define WS 168   // Wl row stride in shorts (k padded 136->160, +8 align pad)
__global__ __launch_bounds__(256) void k2_edge(
    const float* __restrict__ V, const float* __restrict__ T,
    const float* __restrict__ semb, const float* __restrict__ w1,
    const float* __restrict__ b1, const float* __restrict__ w2,
    const float* __restrict__ b2, const int* __restrict__ eidx,
    const int* __restrict__ esign, float* __restrict__ agg,
    float* __restrict__ loss)
{
  __shared__ unsigned short Wl[128*WS];   // w1 [hid][k] bf16; k 136..159 zero
  const int tid = threadIdx.x;
  for (int idx = tid; idx < 128*17; idx += 256) {
    int c = idx / 17, kc = (idx % 17) * 8;
    const float* src = w1 + c*136 + kc;
    *(u16x8*)&Wl[c*WS + kc] = pack2(*(const float4*)src, *(const float4*)(src+4));
  }
  for (int idx = tid; idx < 128*3; idx += 256) {
    int c = idx / 3, s = idx - c*3;
    *(u16x8*)&Wl[c*WS + 136 + s*8] = zero8();
  }
  __syncthreads();
  const int wid = tid >> 6, l = tid & 63, l15 = l & 15, lh = l >> 4;
  float b1v[8], w2v[8];
  #pragma unroll
  for (int n = 0; n < 8; ++n) { b1v[n] = b1[n*16 + l15]; w2v[n] = w2[n*16 + l15]; }
  const float b2v = b2[0];
  float loss_acc = 0.f;
  const int wg = blockIdx.x*4 + wid, nw = gridDim.x*4;

  for (int t = wg; t < NT32; t += nw) {
    const int eb = t * 32;
    const int e0 = eb + l15, e1 = e0 + 16;
    const int r0 = eidx[e0], c0 = eidx[NE + e0], sg0 = esign[e0];
    const int r1 = eidx[e1], c1 = eidx[NE + e1], sg1 = esign[e1];
    const float* t0 = T + c0*64 + lh*8;
    const float* v0 = V + r0*64 + lh*8;
    const float* t1 = T + c1*64 + lh*8;
    const float* v1 = V + r1*64 + lh*8;
    bf16x8 A0[5], A1[5];
    A0[0] = (bf16x8)pack2(*(const float4*)t0,        *(const float4*)(t0+4));
    A0[1] = (bf16x8)pack2(*(const float4*)(t0+32),   *(const float4*)(t0+36));
    A0[2] = (bf16x8)pack2(*(const float4*)v0,        *(const float4*)(v0+4));
    A0[3] = (bf16x8)pack2(*(const float4*)(v0+32),   *(const float4*)(v0+36));
    A1[0] = (bf16x8)pack2(*(const float4*)t1,        *(const float4*)(t1+4));
    A1[1] = (bf16x8)pack2(*(const float4*)(t1+32),   *(const float4*)(t1+36));
    A1[2] = (bf16x8)pack2(*(const float4*)v1,        *(const float4*)(v1+4));
    A1[3] = (bf16x8)pack2(*(const float4*)(v1+32),   *(const float4*)(v1+36));
    if (lh == 0) {
      const float* sp0 = semb + (sg0 + 1) * 8;
      const float* sp1 = semb + (sg1 + 1) * 8;
      A0[4] = (bf16x8)pack2(*(const float4*)sp0, *(const float4*)(sp0+4));
      A1[4] = (bf16x8)pack2(*(const float4*)sp1, *(const float4*)(sp1+4));
    } else {
      A0[4] = (bf16x8)zero8();
      A1[4] = (bf16x8)zero8();
    }

    f32x4 acc0[8], acc1[8];
    #pragma unroll
    for (int n = 0; n < 8; ++n) { acc0[n] = zero4(); acc1[n] = zero4(); }
    #pragma unroll
    for (int ks = 0; ks < 5; ++ks) {
      const int kb = ks*32 + lh*8;
      #pragma unroll
      for (int n = 0; n < 8; ++n) {
        bf16x8 B = *(const bf16x8*)&Wl[(n*16 + l15)*WS + kb];
        acc0[n] = MFMA(A0[ks], B, acc0[n]);
        acc1[n] = MFMA(A1[ks], B, acc1[n]);
      }
    }

    // relu + w2-dot (in-lane over 8 n-tiles), then reduce over the 16 l15 lanes.
    f32x4 s0, s1;
    #pragma unroll
    for (int r = 0; r < 4; ++r) {
      float a = 0.f, b = 0.f;
      #pragma unroll
      for (int n = 0; n < 8; ++n) {
        float h0 = acc0[n][r] + b1v[n]; h0 = fmaxf(h0, 0.f);
        float h1 = acc1[n][r] + b1v[n]; h1 = fmaxf(h1, 0.f);
        a = fmaf(h0, w2v[n], a);
        b = fmaf(h1, w2v[n], b);
      }
      s0[r] = a; s1[r] = b;
    }
    #pragma unroll
    for (int off = 1; off < 16; off <<= 1) {
      #pragma unroll
      for (int r = 0; r < 4; ++r) {
        s0[r] += __shfl_xor(s0[r], off, 16);
        s1[r] += __shfl_xor(s1[r], off, 16);
      }
    }
    // lane (l15,lh) now holds alpha for edges (m*16 + lh*4 + r)
    f32x4 sa0, sa1;
    #pragma unroll
    for (int r = 0; r < 4; ++r) {
      float a0 = s0[r] + b2v;
      float a1 = s1[r] + b2v;
      sa0[r] = (a0 > LAM) ? (a0 - LAM) : ((a0 < -LAM) ? (a0 + LAM) : 0.f);
      sa1[r] = (a1 > LAM) ? (a1 - LAM) : ((a1 < -LAM) ? (a1 + LAM) : 0.f);
    }
    if (l15 == 0) {
      #pragma unroll
      for (int r = 0; r < 4; ++r) loss_acc += fabsf(sa0[r]) + fabsf(sa1[r]);
    }
    // broadcast softshrunk alpha back to this lane's gathered edge (e = l15)
    const int src = (l15 >> 2) << 4;   // lane with lh' = l15>>2, l15'=0
    float q00 = __shfl(sa0[0], src, 64), q01 = __shfl(sa0[1], src, 64);
    float q02 = __shfl(sa0[2], src, 64), q03 = __shfl(sa0[3], src, 64);
    float q10 = __shfl(sa1[0], src, 64), q11 = __shfl(sa1[1], src, 64);
    float q12 = __shfl(sa1[2], src, 64), q13 = __shfl(sa1[3], src, 64);
    const int rs = l15 & 3;
    const float sae0 = (rs==0) ? q00 : (rs==1) ? q01 : (rs==2) ? q02 : q03;
    const float sae1 = (rs==0) ? q10 : (rs==1) ? q11 : (rs==2) ? q12 : q13;
    const float we0 = (sg0 > 0) ? sae0 : ((sg0 < 0) ? -fabsf(sae0) : 0.f);
    const float we1 = (sg1 > 0) ? sae1 : ((sg1 < 0) ? -fabsf(sae1) : 0.f);

    if (we0 != 0.f) {
      float* base = agg + c0*64 + lh*8;
      u16x8 va = (u16x8)A0[2], vb = (u16x8)A0[3];
      #pragma unroll
      for (int j = 0; j < 8; ++j) atomicAdd(base + j,      we0 * bf2f(va[j]));
      #pragma unroll
      for (int j = 0; j < 8; ++j) atomicAdd(base + 32 + j, we0 * bf2f(vb[j]));
    }
    if (we1 != 0.f) {
      float* base = agg + c1*64 + lh*8;
      u16x8 va = (u16x8)A1[2], vb = (u16x8)A1[3];
      #pragma unroll
      for (int j = 0; j < 8; ++j) atomicAdd(base + j,      we1 * bf2f(va[j]));
      #pragma unroll
      for (int j = 0; j < 8; ++j) atomicAdd(base + 32 + j, we1 * bf2f(vb[j]));
    }
  }
  #pragma unroll
  for (int off = 1; off < 64; off <<= 1) loss_acc += __shfl_xor(loss_acc, off, 64);
  if (l == 0) atomicAdd(loss, loss_acc);
}

// ============ Kernel 3: out = [H|agg] @ [Wself|Wout]^T + b + H (unchanged) ============
#define K3S 200
__global__ __launch_bounds__(256) void k3_out(
    const float* __restrict__ H, const float* __restrict__ agg,
    const float* __restrict__ Wself, const float* __restrict__ Wout,
    const float* __restrict__ Wob, const float* __restrict__ loss,
    float* __restrict__ out)
{
  __shared__ unsigned short Wl[128*K3S];
  __shared__ unsigned short Hs[64*K3S];
  const int tid = threadIdx.x;
  for (int idx = tid; idx < 128*24; idx += 256) {
    int c = idx / 24, k = (idx % 24) * 8;
    const float* src = (k < 128) ? (Wself + c*128 + k) : (Wout + c*64 + (k-128));
    *(u16x8*)&Wl[c*K3S + k] = pack2(*(const float4*)src, *(const float4*)(src+4));
  }
  __syncthreads();
  const int wv = tid >> 6, l = tid & 63, l15 = l & 15, lh = l >> 4;
  const float wob0 = Wob[wv*32 + l15], wob1 = Wob[wv*32 + 16 + l15];
  const int ntiles = (NN + 63) >> 6;
  for (int t = blockIdx.x; t < ntiles; t += gridDim.x) {
    const int nb = t * 64;
    {
      const int r = tid >> 2, q = tid & 3, row = nb + r;
      if (row < NN) {
        const float* hsrc = H + row*128 + q*32;
        #pragma unroll
        for (int s = 0; s < 4; ++s)
          *(u16x8*)&Hs[r*K3S + q*32 + s*8] =
              pack2(*(const float4*)(hsrc + s*8), *(const float4*)(hsrc + s*8 + 4));
        const float* asrc = agg + row*64 + q*16;
        #pragma unroll
        for (int s = 0; s < 2; ++s)
          *(u16x8*)&Hs[r*K3S + 128 + q*16 + s*8] =
              pack2(*(const float4*)(asrc + s*8), *(const float4*)(asrc + s*8 + 4));
      } else {
        #pragma unroll
        for (int s = 0; s < 4; ++s) *(u16x8*)&Hs[r*K3S + q*32 + s*8] = zero8();
        #pragma unroll
        for (int s = 0; s < 2; ++s) *(u16x8*)&Hs[r*K3S + 128 + q*16 + s*8] = zero8();
      }
    }
    __syncthreads();
    f32x4 acc[4][2];
    #pragma unroll
    for (int m = 0; m < 4; ++m) { acc[m][0] = zero4(); acc[m][1] = zero4(); }
    #pragma unroll
    for (int kk = 0; kk < 192; kk += 32) {
      const int kb = kk + lh*8;
      bf16x8 bf0 = *(const bf16x8*)&Wl[(wv*32 + l15)*K3S + kb];
      bf16x8 bf1 = *(const bf16x8*)&Wl[(wv*32 + 16 + l15)*K3S + kb];
      #pragma unroll
      for (int m = 0; m < 4; ++m) {
        bf16x8 af = *(const bf16x8*)&Hs[(m*16 + l15)*K3S + kb];
        acc[m][0] = MFMA(af, bf0, acc[m][0]);
        acc[m][1] = MFMA(af, bf1, acc[m][1]);
      }
    }
    #pragma unroll
    for (int m = 0; m < 4; ++m) {
      const int rowl = m*16 + lh*4;
      #pragma unroll
      for (int n = 0; n < 2; ++n) {
        const int col = wv*32 + n*16 + l15;
        const float wob = n ? wob1 : wob0;
        #pragma unroll
        for (int r = 0; r < 4; ++r) {
          const int node = nb + rowl + r;
          if (node < NN)
            out[node*128 + col] = acc[m][n][r] + wob + H[node*128 + col];
        }
      }
    }
    __syncthreads();
  }
  if (blockIdx.x == 0 && tid == 0) out[NN*128] = loss[0] * (1.0f / NE);
}

extern "C" void kernel_launch(void* const* d_in, const int* in_sizes, int n_in,
                              void* d_out, int out_size, void* d_ws, size_t ws_size,
                              hipStream_t stream) {
  const float* H     = (const float*)d_in[0];
  const float* Wv    = (const float*)d_in[1];
  const float* Wt    = (const float*)d_in[2];
  const float* semb  = (const float*)d_in[3];
  const float* w1    = (const float*)d_in[4];
  const float* b1    = (const float*)d_in[5];
  const float* w2    = (const float*)d_in[6];
  const float* b2    = (const float*)d_in[7];
  const float* Wself = (const float*)d_in[8];
  const float* Wout  = (const float*)d_in[9];
  const float* Wob   = (const float*)d_in[10];
  const int*   eidx  = (const int*)d_in[11];
  const int*   esign = (const int*)d_in[12];
  float* out = (float*)d_out;

  float* agg  = (float*)d_ws;                       // 100000*64 f32
  float* loss = (float*)((char*)d_ws + 25600000);   // 1 f32
  float* V = out;                                   // scratch in d_out, overwritten by k3
  float* T = out + 6400000;

  (void)hipMemsetAsync(d_ws, 0, 25600004, stream);
  k1_vt  <<<768, 256, 0, stream>>>(H, Wv, Wt, V, T);
  k2_edge<<<1024, 256, 0, stream>>>(V, T, semb, w1, b1, w2, b2, eidx, esign, agg, loss);
  k3_out <<<512, 256, 0, stream>>>(H, agg, Wself, Wout, Wob, loss, out);
}

// Round 5
// 416.987 us; speedup vs baseline: 4.5527x; 4.5527x over previous
//
#include <hip/hip_runtime.h>

#define NN 100000
#define NE 1600000
#define LAM 0.05f

typedef __attribute__((ext_vector_type(8))) short bf16x8;
typedef __attribute__((ext_vector_type(8))) unsigned short u16x8;
typedef __attribute__((ext_vector_type(4))) float f32x4;
typedef unsigned short ushort_t;

__device__ inline unsigned short f2bf(float x) {
  unsigned u = __builtin_bit_cast(unsigned, x);
  u = (u + 0x7FFFu + ((u >> 16) & 1u)) >> 16;
  return (unsigned short)u;
}
__device__ inline float bf2f(unsigned short h) {
  unsigned u = ((unsigned)h) << 16;
  return __builtin_bit_cast(float, u);
}
__device__ inline u16x8 pack2(float4 a, float4 b) {
  u16x8 p;
  p[0]=f2bf(a.x); p[1]=f2bf(a.y); p[2]=f2bf(a.z); p[3]=f2bf(a.w);
  p[4]=f2bf(b.x); p[5]=f2bf(b.y); p[6]=f2bf(b.z); p[7]=f2bf(b.w);
  return p;
}
__device__ inline u16x8 zero8() {
  u16x8 z;
  #pragma unroll
  for (int i = 0; i < 8; ++i) z[i] = 0;
  return z;
}
__device__ inline f32x4 zero4() {
  f32x4 z;
  z[0] = z[1] = z[2] = z[3] = 0.f;
  return z;
}

#define MFMA(a,b,c) __builtin_amdgcn_mfma_f32_16x16x32_bf16((bf16x8)(a),(bf16x8)(b),(c),0,0,0)

// ============ Kernel 1: V|T = H @ [Wv|Wt]^T via MFMA, bf16 output ============
#define K1S 136
__global__ __launch_bounds__(256) void k1_vt(
    const float* __restrict__ H, const float* __restrict__ Wv,
    const float* __restrict__ Wt, ushort_t* __restrict__ V, ushort_t* __restrict__ T)
{
  __shared__ unsigned short Wl[128*K1S];
  __shared__ unsigned short Hs[64*K1S];
  const int tid = threadIdx.x;
  for (int idx = tid; idx < 128*16; idx += 256) {
    int c = idx >> 4, k = (idx & 15) * 8;
    const float* src = (c < 64) ? (Wv + c*128 + k) : (Wt + (c-64)*128 + k);
    *(u16x8*)&Wl[c*K1S + k] = pack2(*(const float4*)src, *(const float4*)(src+4));
  }
  __syncthreads();
  const int wv = tid >> 6, l = tid & 63, l15 = l & 15, lh = l >> 4;
  const int ntiles = (NN + 63) >> 6;
  for (int t = blockIdx.x; t < ntiles; t += gridDim.x) {
    const int nb = t * 64;
    {
      const int r = tid >> 2, q = tid & 3, row = nb + r;
      if (row < NN) {
        const float* src = H + row*128 + q*32;
        #pragma unroll
        for (int s = 0; s < 4; ++s)
          *(u16x8*)&Hs[r*K1S + q*32 + s*8] =
              pack2(*(const float4*)(src + s*8), *(const float4*)(src + s*8 + 4));
      } else {
        #pragma unroll
        for (int s = 0; s < 4; ++s) *(u16x8*)&Hs[r*K1S + q*32 + s*8] = zero8();
      }
    }
    __syncthreads();
    f32x4 acc[4][2];
    #pragma unroll
    for (int m = 0; m < 4; ++m) { acc[m][0] = zero4(); acc[m][1] = zero4(); }
    #pragma unroll
    for (int kk = 0; kk < 128; kk += 32) {
      const int kb = kk + lh*8;
      bf16x8 bf0 = *(const bf16x8*)&Wl[(wv*32 + l15)*K1S + kb];
      bf16x8 bf1 = *(const bf16x8*)&Wl[(wv*32 + 16 + l15)*K1S + kb];
      #pragma unroll
      for (int m = 0; m < 4; ++m) {
        bf16x8 af = *(const bf16x8*)&Hs[(m*16 + l15)*K1S + kb];
        acc[m][0] = MFMA(af, bf0, acc[m][0]);
        acc[m][1] = MFMA(af, bf1, acc[m][1]);
      }
    }
    #pragma unroll
    for (int m = 0; m < 4; ++m) {
      const int rowl = m*16 + lh*4;
      #pragma unroll
      for (int n = 0; n < 2; ++n) {
        const int col = wv*32 + n*16 + l15;
        #pragma unroll
        for (int r = 0; r < 4; ++r) {
          const int node = nb + rowl + r;
          if (node < NN) {
            if (col < 64) V[node*64 + col] = f2bf(acc[m][n][r]);
            else          T[node*64 + col - 64] = f2bf(acc[m][n][r]);
          }
        }
      }
    }
    __syncthreads();
  }
}

// ============ Kernel 2: barrier-free wave-autonomous edge MLP + scatter ============
// Each wave owns 16 edges/tile: stages them into its private LDS X slice
// (coalesced 16B copies of bf16 V/T rows), runs the full 136->128->1 MLP via
// MFMA (one m-tile, 8 n-tiles), softshrinks in-register, scatters with
// 64-lane-per-edge coalesced atomics. No __syncthreads in the loop.
#define WS 168
__global__ __launch_bounds__(256) void k2_edge(
    const ushort_t* __restrict__ V, const ushort_t* __restrict__ T,
    const float* __restrict__ semb, const float* __restrict__ w1,
    const float* __restrict__ b1, const float* __restrict__ w2,
    const float* __restrict__ b2, const int* __restrict__ eidx,
    const int* __restrict__ esign, float* __restrict__ agg,
    float* __restrict__ loss)
{
  __shared__ unsigned short Wl[128*WS];      // w1 bf16 [hid][k], k 136..159 zero
  __shared__ unsigned short X[4][16*WS];     // per-wave [edge][T|V|semb|pad0]
  const int tid = threadIdx.x;
  for (int idx = tid; idx < 128*17; idx += 256) {
    int c = idx / 17, kc = (idx % 17) * 8;
    const float* src = w1 + c*136 + kc;
    *(u16x8*)&Wl[c*WS + kc] = pack2(*(const float4*)src, *(const float4*)(src+4));
  }
  for (int idx = tid; idx < 128*3; idx += 256) {
    int c = idx / 3, s = idx % 3;
    *(u16x8*)&Wl[c*WS + 136 + s*8] = zero8();
  }
  {  // zero persistent X pad (k=136..167) for all 64 rows
    int r = tid >> 2, s = tid & 3;
    *(u16x8*)&((unsigned short*)X)[r*WS + 136 + s*8] = zero8();
  }
  __syncthreads();

  const int wv = tid >> 6, l = tid & 63, l15 = l & 15, lh = l >> 4;
  unsigned short* Xw = (unsigned short*)X[wv];
  float b1v[8], w2v[8];
  #pragma unroll
  for (int n = 0; n < 8; ++n) { b1v[n] = b1[n*16 + l15]; w2v[n] = w2[n*16 + l15]; }
  const float b2v = b2[0];
  float loss_acc = 0.f;

  const int eloc = l >> 2, q = l & 3;       // staging role: edge eloc, quarter q
  const int wg = blockIdx.x*4 + wv, nw = gridDim.x*4;
  const int NT16 = NE / 16;

  for (int t = wg; t < NT16; t += nw) {
    const int e = t*16 + eloc;
    const int rj = eidx[e], ci = eidx[NE + e], sg = esign[e];
    // ---- stage this wave's 16 edges (bf16 rows, 16B chunks) ----
    *(u16x8*)&Xw[eloc*WS + q*16]       = *(const u16x8*)&T[ci*64 + q*16];
    *(u16x8*)&Xw[eloc*WS + q*16 + 8]   = *(const u16x8*)&T[ci*64 + q*16 + 8];
    *(u16x8*)&Xw[eloc*WS + 64 + q*16]     = *(const u16x8*)&V[rj*64 + q*16];
    *(u16x8*)&Xw[eloc*WS + 64 + q*16 + 8] = *(const u16x8*)&V[rj*64 + q*16 + 8];
    if (q == 0) {
      const float* sp = semb + (sg + 1) * 8;
      *(u16x8*)&Xw[eloc*WS + 128] = pack2(*(const float4*)sp, *(const float4*)(sp+4));
    }
    // ---- MFMA: rows = 16 edges, cols = 128 hid, K = 160 ----
    f32x4 acc[8];
    #pragma unroll
    for (int n = 0; n < 8; ++n) acc[n] = zero4();
    #pragma unroll
    for (int ks = 0; ks < 5; ++ks) {
      const int kb = ks*32 + lh*8;
      bf16x8 A = *(const bf16x8*)&Xw[l15*WS + kb];
      #pragma unroll
      for (int n = 0; n < 8; ++n) {
        bf16x8 B = *(const bf16x8*)&Wl[(n*16 + l15)*WS + kb];
        acc[n] = MFMA(A, B, acc[n]);
      }
    }
    // ---- relu + w2 dot (in-lane over n), reduce over l15 ----
    f32x4 s;
    #pragma unroll
    for (int r = 0; r < 4; ++r) {
      float a = 0.f;
      #pragma unroll
      for (int n = 0; n < 8; ++n) {
        float h = acc[n][r] + b1v[n];
        h = fmaxf(h, 0.f);
        a = fmaf(h, w2v[n], a);
      }
      s[r] = a;
    }
    #pragma unroll
    for (int off = 1; off < 16; off <<= 1) {
      #pragma unroll
      for (int r = 0; r < 4; ++r) s[r] += __shfl_xor(s[r], off, 16);
    }
    // lane(l15,lh): s[r] = alpha for edge lh*4+r (same for all l15)
    f32x4 sa;
    #pragma unroll
    for (int r = 0; r < 4; ++r) {
      float a = s[r] + b2v;
      sa[r] = (a > LAM) ? (a - LAM) : ((a < -LAM) ? (a + LAM) : 0.f);
    }
    if (l15 == 0) {
      #pragma unroll
      for (int r = 0; r < 4; ++r) loss_acc += fabsf(sa[r]);
    }
    // ---- scatter: one coalesced 256B atomic row per edge ----
    #pragma unroll 4
    for (int i = 0; i < 16; ++i) {
      const float sab = __shfl(sa[i & 3], (i >> 2) * 16, 64);
      const int ci_b  = __shfl(ci, i * 4, 64);
      const int sg_b  = __shfl(sg, i * 4, 64);
      const float we = (sg_b > 0) ? sab : ((sg_b < 0) ? -fabsf(sab) : 0.f);
      if (we != 0.f) {
        const float vj = bf2f(Xw[i*WS + 64 + l]);
        atomicAdd(&agg[ci_b*64 + l], we * vj);
      }
    }
  }
  #pragma unroll
  for (int off = 1; off < 64; off <<= 1) loss_acc += __shfl_xor(loss_acc, off, 64);
  if (l == 0) atomicAdd(loss, loss_acc);
}

// ============ Kernel 3: out = [H|agg] @ [Wself|Wout]^T + b + H (unchanged) ============
#define K3S 200
__global__ __launch_bounds__(256) void k3_out(
    const float* __restrict__ H, const float* __restrict__ agg,
    const float* __restrict__ Wself, const float* __restrict__ Wout,
    const float* __restrict__ Wob, const float* __restrict__ loss,
    float* __restrict__ out)
{
  __shared__ unsigned short Wl[128*K3S];
  __shared__ unsigned short Hs[64*K3S];
  const int tid = threadIdx.x;
  for (int idx = tid; idx < 128*24; idx += 256) {
    int c = idx / 24, k = (idx % 24) * 8;
    const float* src = (k < 128) ? (Wself + c*128 + k) : (Wout + c*64 + (k-128));
    *(u16x8*)&Wl[c*K3S + k] = pack2(*(const float4*)src, *(const float4*)(src+4));
  }
  __syncthreads();
  const int wv = tid >> 6, l = tid & 63, l15 = l & 15, lh = l >> 4;
  const float wob0 = Wob[wv*32 + l15], wob1 = Wob[wv*32 + 16 + l15];
  const int ntiles = (NN + 63) >> 6;
  for (int t = blockIdx.x; t < ntiles; t += gridDim.x) {
    const int nb = t * 64;
    {
      const int r = tid >> 2, q = tid & 3, row = nb + r;
      if (row < NN) {
        const float* hsrc = H + row*128 + q*32;
        #pragma unroll
        for (int s = 0; s < 4; ++s)
          *(u16x8*)&Hs[r*K3S + q*32 + s*8] =
              pack2(*(const float4*)(hsrc + s*8), *(const float4*)(hsrc + s*8 + 4));
        const float* asrc = agg + row*64 + q*16;
        #pragma unroll
        for (int s = 0; s < 2; ++s)
          *(u16x8*)&Hs[r*K3S + 128 + q*16 + s*8] =
              pack2(*(const float4*)(asrc + s*8), *(const float4*)(asrc + s*8 + 4));
      } else {
        #pragma unroll
        for (int s = 0; s < 4; ++s) *(u16x8*)&Hs[r*K3S + q*32 + s*8] = zero8();
        #pragma unroll
        for (int s = 0; s < 2; ++s) *(u16x8*)&Hs[r*K3S + 128 + q*16 + s*8] = zero8();
      }
    }
    __syncthreads();
    f32x4 acc[4][2];
    #pragma unroll
    for (int m = 0; m < 4; ++m) { acc[m][0] = zero4(); acc[m][1] = zero4(); }
    #pragma unroll
    for (int kk = 0; kk < 192; kk += 32) {
      const int kb = kk + lh*8;
      bf16x8 bf0 = *(const bf16x8*)&Wl[(wv*32 + l15)*K3S + kb];
      bf16x8 bf1 = *(const bf16x8*)&Wl[(wv*32 + 16 + l15)*K3S + kb];
      #pragma unroll
      for (int m = 0; m < 4; ++m) {
        bf16x8 af = *(const bf16x8*)&Hs[(m*16 + l15)*K3S + kb];
        acc[m][0] = MFMA(af, bf0, acc[m][0]);
        acc[m][1] = MFMA(af, bf1, acc[m][1]);
      }
    }
    #pragma unroll
    for (int m = 0; m < 4; ++m) {
      const int rowl = m*16 + lh*4;
      #pragma unroll
      for (int n = 0; n < 2; ++n) {
        const int col = wv*32 + n*16 + l15;
        const float wob = n ? wob1 : wob0;
        #pragma unroll
        for (int r = 0; r < 4; ++r) {
          const int node = nb + rowl + r;
          if (node < NN)
            out[node*128 + col] = acc[m][n][r] + wob + H[node*128 + col];
        }
      }
    }
    __syncthreads();
  }
  if (blockIdx.x == 0 && tid == 0) out[NN*128] = loss[0] * (1.0f / NE);
}

extern "C" void kernel_launch(void* const* d_in, const int* in_sizes, int n_in,
                              void* d_out, int out_size, void* d_ws, size_t ws_size,
                              hipStream_t stream) {
  const float* H     = (const float*)d_in[0];
  const float* Wv    = (const float*)d_in[1];
  const float* Wt    = (const float*)d_in[2];
  const float* semb  = (const float*)d_in[3];
  const float* w1    = (const float*)d_in[4];
  const float* b1    = (const float*)d_in[5];
  const float* w2    = (const float*)d_in[6];
  const float* b2    = (const float*)d_in[7];
  const float* Wself = (const float*)d_in[8];
  const float* Wout  = (const float*)d_in[9];
  const float* Wob   = (const float*)d_in[10];
  const int*   eidx  = (const int*)d_in[11];
  const int*   esign = (const int*)d_in[12];
  float* out = (float*)d_out;

  float* agg  = (float*)d_ws;                       // 100000*64 f32
  float* loss = (float*)((char*)d_ws + 25600000);   // 1 f32
  // V/T as bf16 scratch inside d_out (25.6MB of 51.2MB); k3 overwrites out fully.
  ushort_t* V = (ushort_t*)out;
  ushort_t* T = V + 6400000;

  (void)hipMemsetAsync(d_ws, 0, 25600004, stream);
  k1_vt  <<<768, 256, 0, stream>>>(H, Wv, Wt, V, T);
  k2_edge<<<512, 256, 0, stream>>>(V, T, semb, w1, b1, w2, b2, eidx, esign, agg, loss);
  k3_out <<<512, 256, 0, stream>>>(H, agg, Wself, Wout, Wob, loss, out);
}